// Round 8
// baseline (703.229 us; speedup 1.0000x reference)
//
#include <hip/hip_runtime.h>

#define N_NODES 50000
#define N_EDGES 800000
#define F_IN 128
#define DIM 256
#define N_GRAPHS 512
#define BN_EPS 1e-5f

typedef unsigned short u16;
typedef unsigned int u32;
using floatx4 = __attribute__((ext_vector_type(4))) float;
using short8 = __attribute__((ext_vector_type(8))) short;
using half2v = __attribute__((ext_vector_type(2))) _Float16;

#if __has_builtin(__builtin_amdgcn_fdot2)
#define HAS_FDOT2 1
#endif

// ---- fp16 helpers (IEEE half; RNE via v_cvt_f16_f32) ----
__device__ __forceinline__ u16 f2h(float f) {
    _Float16 h = (_Float16)f;
    return __builtin_bit_cast(u16, h);
}
__device__ __forceinline__ float hlo(u32 u) {
    half2v h = __builtin_bit_cast(half2v, u);
    return (float)h.x;
}
__device__ __forceinline__ float hhi(u32 u) {
    half2v h = __builtin_bit_cast(half2v, u);
    return (float)h.y;
}
__device__ __forceinline__ u32 pack2(float a, float b) {
    half2v h = {(_Float16)a, (_Float16)b};
    return __builtin_bit_cast(u32, h);
}
// accumulate both halves of a packed-f16 word into two fp32 accumulators.
__device__ __forceinline__ void dacc(u32 w, float& a, float& b) {
#ifdef HAS_FDOT2
    half2v v = __builtin_bit_cast(half2v, w);
    const half2v L = {(_Float16)1.0f, (_Float16)0.0f};
    const half2v Hm = {(_Float16)0.0f, (_Float16)1.0f};
    a = __builtin_amdgcn_fdot2(v, L, a, false);
    b = __builtin_amdgcn_fdot2(v, Hm, b, false);
#else
    a += hlo(w);
    b += hhi(w);
#endif
}
__device__ __forceinline__ void load_lds16(const void* g, void* l) {
    __builtin_amdgcn_global_load_lds((const __attribute__((address_space(1))) void*)g,
                                     (__attribute__((address_space(3))) void*)l, 16, 0, 0);
}

// ---------------- CSR build ----------------

__global__ void count_deg(const int* __restrict__ dst, int* __restrict__ deg, int nE) {
    int e = blockIdx.x * 256 + threadIdx.x;
    if (e < nE) atomicAdd(&deg[dst[e]], 1);
}

__global__ void scan_block(const int* __restrict__ deg, int* __restrict__ row_start,
                           int* __restrict__ bsum, int n) {
    __shared__ int wtot[4];
    int i = blockIdx.x * 256 + threadIdx.x;
    int lane = threadIdx.x & 63, w = threadIdx.x >> 6;
    int v = (i < n) ? deg[i] : 0;
    int s = v;
#pragma unroll
    for (int d = 1; d < 64; d <<= 1) {
        int t = __shfl_up(s, d);
        if (lane >= d) s += t;
    }
    if (lane == 63) wtot[w] = s;
    __syncthreads();
    int off = 0;
#pragma unroll
    for (int k = 0; k < 4; ++k)
        if (k < w) off += wtot[k];
    s += off;
    if (i < n) row_start[i + 1] = s;
    if (threadIdx.x == 255) bsum[blockIdx.x] = s;
}

__global__ void scan_partials(const int* __restrict__ bsum, int* __restrict__ boff,
                              int* __restrict__ row_start, int* __restrict__ cursor, int nb) {
    __shared__ int wtot[4];
    int i = threadIdx.x;
    int lane = i & 63, w = i >> 6;
    int v = (i < nb) ? bsum[i] : 0;
    int s = v;
#pragma unroll
    for (int d = 1; d < 64; d <<= 1) {
        int t = __shfl_up(s, d);
        if (lane >= d) s += t;
    }
    if (lane == 63) wtot[w] = s;
    __syncthreads();
    int off = 0;
#pragma unroll
    for (int k = 0; k < 4; ++k)
        if (k < w) off += wtot[k];
    boff[i] = s + off - v;
    if (i == 0) { row_start[0] = 0; cursor[0] = 0; }
}

__global__ void add_offsets(int* __restrict__ row_start, int* __restrict__ cursor,
                            const int* __restrict__ boff, int n) {
    int i = blockIdx.x * 256 + threadIdx.x;
    if (i < n) {
        int fin = row_start[i + 1] + boff[blockIdx.x];
        row_start[i + 1] = fin;
        cursor[i + 1] = fin;
    }
}

__global__ void fill_csr(const int* __restrict__ src, const int* __restrict__ dst,
                         int* __restrict__ cursor, int* __restrict__ srcs, int nE) {
    int e = blockIdx.x * 256 + threadIdx.x;
    if (e < nE) {
        int p = atomicAdd(&cursor[dst[e]], 1);
        srcs[p] = src[e];
    }
}

// ---------------- one-shot converts: x -> f16 H, all 6 weights -> transposed f16 ----------------
// segment bases (u16 elems in Wall): w1_0@0 (K=128), w1_1@32768, w1_2@98304,
// w2_0@163840, w2_1@229376, w2_2@294912 ; total 360448

__global__ void convert_all(const float4* __restrict__ x4, uint2* __restrict__ Hout, int n4,
                            const float* __restrict__ w10, const float* __restrict__ w11,
                            const float* __restrict__ w12, const float* __restrict__ w20,
                            const float* __restrict__ w21, const float* __restrict__ w22,
                            u16* __restrict__ Wall) {
    int i = blockIdx.x * 256 + threadIdx.x;
    if (i < n4) {
        float4 v = x4[i];
        uint2 p;
        p.x = pack2(v.x, v.y);
        p.y = pack2(v.z, v.w);
        Hout[i] = p;
        return;
    }
    int j = i - n4;
    if (j >= 360448) return;
    const float* w;
    int K, base;
    if (j < 32768)       { w = w10; K = 128; base = 0; }
    else if (j < 98304)  { w = w11; K = 256; base = 32768; }
    else if (j < 163840) { w = w12; K = 256; base = 98304; }
    else if (j < 229376) { w = w20; K = 256; base = 163840; }
    else if (j < 294912) { w = w21; K = 256; base = 229376; }
    else                 { w = w22; K = 256; base = 294912; }
    int loc = j - base;
    int nn = loc / K, kk = loc - nn * K;
    Wall[j] = f2h(w[(size_t)kk * 256 + nn]);
}

// ---------------- aggregation (f16 gather): agg = h_i + sum_j h_j ----------------
// One wave per node. Lanes split into NSUB row-groups; each group reads a DIFFERENT neighbor
// row as uint4 (16B/lane) -> 1KiB/instruction; up to 8 gathers in flight per wave.
// Gather is at the structural floor (queue-depth x LLC latency) per rounds 2/5/6.

template <int K>
__global__ __launch_bounds__(256) void aggregate_v2(
    const u16* __restrict__ h, const int* __restrict__ row_start,
    const int* __restrict__ srcs, u16* __restrict__ outp, int n) {
    constexpr int RW = K / 2;                 // u32 per row (128 or 64)
    constexpr int NSUB = (K == 256) ? 2 : 4;  // rows per gather instruction
    int node = (int)(((size_t)blockIdx.x * blockDim.x + threadIdx.x) >> 6);
    int lane = threadIdx.x & 63;
    if (node >= n) return;
    const u32* hb = (const u32*)h;
    const int sub = lane / (64 / NSUB);       // row-group within the wave
    const int li = lane % (64 / NSUB);        // 16B chunk index within row

    float acc[8];
#pragma unroll
    for (int t = 0; t < 8; ++t) acc[t] = 0.f;
    {
        // self row: only the sub==0 lanes contribute (others stay 0)
        if (sub == 0) {
            uint4 v = *(const uint4*)(hb + (size_t)node * RW + li * 4);
            dacc(v.x, acc[0], acc[1]);
            dacc(v.y, acc[2], acc[3]);
            dacc(v.z, acc[4], acc[5]);
            dacc(v.w, acc[6], acc[7]);
        }
    }

    int s = row_start[node], e = row_start[node + 1];
    for (int j0 = s; j0 < e; j0 += 64) {
        int myidx = (j0 + lane < e) ? srcs[j0 + lane] : 0;
        int cnt = min(64, e - j0);
        int j = 0;
        for (; j + NSUB * 8 - 1 < cnt; j += NSUB * 8) {  // 8 gathers in flight
            uint4 g[8];
#pragma unroll
            for (int q = 0; q < 8; ++q) {
                int sq = __shfl(myidx, j + q * NSUB + sub);
                g[q] = *(const uint4*)(hb + (size_t)sq * RW + li * 4);
            }
#pragma unroll
            for (int q = 0; q < 8; ++q) {
                dacc(g[q].x, acc[0], acc[1]);
                dacc(g[q].y, acc[2], acc[3]);
                dacc(g[q].z, acc[4], acc[5]);
                dacc(g[q].w, acc[6], acc[7]);
            }
        }
        for (; j + NSUB * 4 - 1 < cnt; j += NSUB * 4) {  // 4 in flight
            uint4 g[4];
#pragma unroll
            for (int q = 0; q < 4; ++q) {
                int sq = __shfl(myidx, j + q * NSUB + sub);
                g[q] = *(const uint4*)(hb + (size_t)sq * RW + li * 4);
            }
#pragma unroll
            for (int q = 0; q < 4; ++q) {
                dacc(g[q].x, acc[0], acc[1]);
                dacc(g[q].y, acc[2], acc[3]);
                dacc(g[q].z, acc[4], acc[5]);
                dacc(g[q].w, acc[6], acc[7]);
            }
        }
        for (; j < cnt; j += NSUB) {  // predicated remainder, NSUB rows at a time
            int idx = j + sub;
            bool valid = idx < cnt;
            int sq = __shfl(myidx, valid ? idx : j);
            if (valid) {
                uint4 g = *(const uint4*)(hb + (size_t)sq * RW + li * 4);
                dacc(g.x, acc[0], acc[1]);
                dacc(g.y, acc[2], acc[3]);
                dacc(g.z, acc[4], acc[5]);
                dacc(g.w, acc[6], acc[7]);
            }
        }
    }

    // fold partial sums across row-groups
    if (NSUB == 4) {
#pragma unroll
        for (int t = 0; t < 8; ++t) acc[t] += __shfl_xor(acc[t], 16);
    }
#pragma unroll
    for (int t = 0; t < 8; ++t) acc[t] += __shfl_xor(acc[t], 32);

    if (sub == 0) {
        uint4 o;
        o.x = pack2(acc[0], acc[1]);
        o.y = pack2(acc[2], acc[3]);
        o.z = pack2(acc[4], acc[5]);
        o.w = pack2(acc[6], acc[7]);
        *(uint4*)((u32*)outp + (size_t)node * RW + li * 4) = o;
    }
}

// ---------------- fused MLP: m = relu(relu(A@W1+b1)@W2+b2), f16 out + BN sums ----------------
// 64-row tile, 512 threads = 8 waves (2m x 4n), wave tile 32x64 (acc[2][4] of 16x16x32).
// Phase 1: GEMM1 -> Ts (LDS, 32KB) with XOR-swizzle (16B chunk ^= row&7) so phase-2
// ds_read_b128 A-fragments at 512B row stride are ~2-way (free) instead of 32-way.
// Phase 2: GEMM2 with A from Ts, B staged from W2. Epilogue = round-4 BN-sums pattern.
// NOTE (round-7 bug): Cout must NOT alias A. At layer 0 A-rows are 128 u16 but C-rows are
// 256 u16 -> block 0's C writes cover block 1's A rows (cross-block race, absmax 141).
// Cout now goes to a dedicated buffer (Mb).

template <int K1>
__global__ __launch_bounds__(512, 4) void mlp_fused(
    const u16* __restrict__ A, const u16* __restrict__ B1t, const float* __restrict__ b1,
    const u16* __restrict__ B2t, const float* __restrict__ b2,
    u16* __restrict__ Cout, float* __restrict__ sums, int M) {
    __shared__ u16 As[64 * 32];    // 4 KB
    __shared__ u16 Bs[256 * 32];   // 16 KB (W1 then W2 staging)
    __shared__ u16 Ts[64 * 256];   // 32 KB, XOR-swizzled 16B chunks
    const int tid = threadIdx.x;
    const int w = tid >> 6, lane = tid & 63;
    const int wm = w >> 2, wn = w & 3;
    const int r = lane & 15, rg = lane >> 4;
    const int bm = blockIdx.x * 64;

    floatx4 acc[2][4];
#pragma unroll
    for (int i = 0; i < 2; ++i)
#pragma unroll
        for (int j = 0; j < 4; ++j) acc[i][j] = (floatx4){0.f, 0.f, 0.f, 0.f};

    // ---- phase 1: T = relu(A @ W1^T + b1) -> Ts ----
    for (int k0 = 0; k0 < K1; k0 += 32) {
        __syncthreads();
        if (tid < 256) {  // waves 0-3 stage the 64x32 A tile (1KB per wave)
            int arow = bm + (tid >> 2);
            if (arow >= M) arow = M - 1;
            load_lds16(A + (size_t)arow * K1 + k0 + (tid & 3) * 8, As + w * 512);
        }
#pragma unroll
        for (int q = 0; q < 2; ++q) {
            int i = q * 512 + tid;
            load_lds16(B1t + (size_t)(i >> 2) * K1 + k0 + (i & 3) * 8, Bs + (q * 8 + w) * 512);
        }
        __syncthreads();
        short8 a[2], b[4];
#pragma unroll
        for (int mi = 0; mi < 2; ++mi)
            a[mi] = *(const short8*)(As + (wm * 32 + mi * 16 + r) * 32 + rg * 8);
#pragma unroll
        for (int ni = 0; ni < 4; ++ni)
            b[ni] = *(const short8*)(Bs + (wn * 64 + ni * 16 + r) * 32 + rg * 8);
#pragma unroll
        for (int mi = 0; mi < 2; ++mi)
#pragma unroll
            for (int ni = 0; ni < 4; ++ni)
                acc[mi][ni] = __builtin_amdgcn_mfma_f32_16x16x32_f16(a[mi], b[ni], acc[mi][ni], 0, 0, 0);
    }
    // epilogue 1: relu+bias, f16-quantize, swizzled store into Ts
#pragma unroll
    for (int ni = 0; ni < 4; ++ni) {
        int col = wn * 64 + ni * 16 + r;
        float bv = b1[col];
#pragma unroll
        for (int mi = 0; mi < 2; ++mi)
#pragma unroll
            for (int rr = 0; rr < 4; ++rr) {
                int lrow = wm * 32 + mi * 16 + rg * 4 + rr;
                float v = fmaxf(acc[mi][ni][rr] + bv, 0.f);
                int chunk = (col >> 3) ^ (lrow & 7);
                *(u16*)((char*)Ts + lrow * 512 + chunk * 16 + (col & 7) * 2) = f2h(v);
            }
        // reset accumulators for phase 2
#pragma unroll
        for (int mi = 0; mi < 2; ++mi) acc[mi][ni] = (floatx4){0.f, 0.f, 0.f, 0.f};
    }

    // ---- phase 2: m = relu(T @ W2^T + b2) ----
    for (int k0 = 0; k0 < 256; k0 += 32) {
        __syncthreads();  // first iter: Ts complete; later: Bs consumed
#pragma unroll
        for (int q = 0; q < 2; ++q) {
            int i = q * 512 + tid;
            load_lds16(B2t + (size_t)(i >> 2) * 256 + k0 + (i & 3) * 8, Bs + (q * 8 + w) * 512);
        }
        __syncthreads();
        short8 a[2], b[4];
#pragma unroll
        for (int mi = 0; mi < 2; ++mi) {
            int lrow = wm * 32 + mi * 16 + r;
            int chunk = ((k0 >> 3) + rg) ^ (lrow & 7);
            a[mi] = *(const short8*)((const char*)Ts + lrow * 512 + chunk * 16);
        }
#pragma unroll
        for (int ni = 0; ni < 4; ++ni)
            b[ni] = *(const short8*)(Bs + (wn * 64 + ni * 16 + r) * 32 + rg * 8);
#pragma unroll
        for (int mi = 0; mi < 2; ++mi)
#pragma unroll
            for (int ni = 0; ni < 4; ++ni)
                acc[mi][ni] = __builtin_amdgcn_mfma_f32_16x16x32_f16(a[mi], b[ni], acc[mi][ni], 0, 0, 0);
    }

    // epilogue 2: relu+bias, f16 out (stats on quantized values), fused BN partial sums
#pragma unroll
    for (int ni = 0; ni < 4; ++ni) {
        int col = wn * 64 + ni * 16 + r;
        float bv = b2[col];
        float s = 0.f, s2 = 0.f;
#pragma unroll
        for (int mi = 0; mi < 2; ++mi)
#pragma unroll
            for (int rr = 0; rr < 4; ++rr) {
                int row = bm + wm * 32 + mi * 16 + rg * 4 + rr;
                if (row < M) {
                    float v = fmaxf(acc[mi][ni][rr] + bv, 0.f);
                    u16 qb = f2h(v);
                    float vq = hlo((u32)qb);
                    Cout[(size_t)row * 256 + col] = qb;
                    s += vq;
                    s2 += vq * vq;
                }
            }
        s += __shfl_xor(s, 16);
        s += __shfl_xor(s, 32);
        s2 += __shfl_xor(s2, 16);
        s2 += __shfl_xor(s2, 32);
        if (rg == 0) {
            atomicAdd(&sums[col], s);
            atomicAdd(&sums[256 + col], s2);
        }
    }
}

// ---------------- BN finalize+apply + f16 re-pack + fused per-graph pooling ----------------
// Reads f16 m, applies affine in fp32, writes fp32 out_nodes (nontemporal: never re-read)
// + f16 H (next layer's gather input) + pooled atomics.

template <int WRITE_H>
__global__ void bn_apply_pool(const u16* __restrict__ Mb, const float* __restrict__ sums,
                              const float* __restrict__ g, const float* __restrict__ bb,
                              const int* __restrict__ batch, float* __restrict__ out_nodes,
                              u16* __restrict__ H, float* __restrict__ pooled,
                              int col_off, int n, float inv_n) {
    int w = threadIdx.x >> 6, lane = threadIdx.x & 63;
    int base = blockIdx.x * 64 + w * 16;
    if (base >= n) return;
    int c4 = lane << 2;
    float4 s1 = *(const float4*)(sums + c4);
    float4 s2 = *(const float4*)(sums + 256 + c4);
    float4 g4 = *(const float4*)(g + c4);
    float4 b4 = *(const float4*)(bb + c4);
    float4 sc, sh;
    {
        float mux = s1.x * inv_n, muy = s1.y * inv_n, muz = s1.z * inv_n, muw = s1.w * inv_n;
        sc.x = g4.x / sqrtf(s2.x * inv_n - mux * mux + BN_EPS);
        sc.y = g4.y / sqrtf(s2.y * inv_n - muy * muy + BN_EPS);
        sc.z = g4.z / sqrtf(s2.z * inv_n - muz * muz + BN_EPS);
        sc.w = g4.w / sqrtf(s2.w * inv_n - muw * muw + BN_EPS);
        sh.x = b4.x - mux * sc.x;
        sh.y = b4.y - muy * sc.y;
        sh.z = b4.z - muz * sc.z;
        sh.w = b4.w - muw * sc.w;
    }
    float4 acc = make_float4(0.f, 0.f, 0.f, 0.f);
    int gcur = -1;
    int end = min(base + 16, n);
    for (int row = base; row < end; ++row) {
        uint2 pk = *(const uint2*)(Mb + (size_t)row * 256 + c4);
        float4 o;
        o.x = fmaf(hlo(pk.x), sc.x, sh.x);
        o.y = fmaf(hhi(pk.x), sc.y, sh.y);
        o.z = fmaf(hlo(pk.y), sc.z, sh.z);
        o.w = fmaf(hhi(pk.y), sc.w, sh.w);
        floatx4 ov = {o.x, o.y, o.z, o.w};
        __builtin_nontemporal_store(ov, (floatx4*)(out_nodes + (size_t)row * 768 + col_off + c4));
        if (WRITE_H) {
            uint2 hk;
            hk.x = pack2(o.x, o.y);
            hk.y = pack2(o.z, o.w);
            *(uint2*)(H + (size_t)row * 256 + c4) = hk;
        }
        int gg = batch[row];
        if (gg != gcur) {
            if (gcur >= 0) {
                float* pp = pooled + (size_t)gcur * 768 + col_off + c4;
                atomicAdd(pp + 0, acc.x);
                atomicAdd(pp + 1, acc.y);
                atomicAdd(pp + 2, acc.z);
                atomicAdd(pp + 3, acc.w);
            }
            gcur = gg;
            acc = o;
        } else {
            acc.x += o.x; acc.y += o.y; acc.z += o.z; acc.w += o.w;
        }
    }
    if (gcur >= 0) {
        float* pp = pooled + (size_t)gcur * 768 + col_off + c4;
        atomicAdd(pp + 0, acc.x);
        atomicAdd(pp + 1, acc.y);
        atomicAdd(pp + 2, acc.z);
        atomicAdd(pp + 3, acc.w);
    }
}

// ---------------- launch ----------------

extern "C" void kernel_launch(void* const* d_in, const int* in_sizes, int n_in,
                              void* d_out, int out_size, void* d_ws, size_t ws_size,
                              hipStream_t stream) {
    const float* x = (const float*)d_in[0];
    const int* esrc = (const int*)d_in[1];
    const int* edst = esrc + N_EDGES;
    const int* batch = (const int*)d_in[2];

    const float* w1[3] = {(const float*)d_in[3], (const float*)d_in[9], (const float*)d_in[15]};
    const float* b1[3] = {(const float*)d_in[4], (const float*)d_in[10], (const float*)d_in[16]};
    const float* w2[3] = {(const float*)d_in[5], (const float*)d_in[11], (const float*)d_in[17]};
    const float* b2[3] = {(const float*)d_in[6], (const float*)d_in[12], (const float*)d_in[18]};
    const float* bng[3] = {(const float*)d_in[7], (const float*)d_in[13], (const float*)d_in[19]};
    const float* bnb[3] = {(const float*)d_in[8], (const float*)d_in[14], (const float*)d_in[20]};

    float* out_pooled = (float*)d_out;
    float* out_nodes = (float*)d_out + (size_t)N_GRAPHS * 768;

    char* p = (char*)d_ws;
    u16* Abf = (u16*)p; p += (size_t)N_NODES * 256 * 2;  // aggregate out (MLP input)
    u16* Mb = (u16*)p;  p += (size_t)N_NODES * 256 * 2;  // fused-MLP m out (pre-BN)
    u16* H = (u16*)p;   p += (size_t)N_NODES * 256 * 2;  // f16 node feats
    u16* Wall = (u16*)p; p += (size_t)360448 * 2;        // all transposed weights
    // zero region: [sums x3 | deg]  (one memset)
    float* sums = (float*)p; p += 3 * 512 * 4;
    int* deg = (int*)p;      p += (size_t)N_NODES * 4;
    const size_t zero_bytes = 3 * 512 * 4 + (size_t)N_NODES * 4;
    int* row_start = (int*)p; p += (size_t)(N_NODES + 1) * 4;
    int* cursor = (int*)p;    p += (size_t)(N_NODES + 1) * 4;
    int* srcs = (int*)p;      p += (size_t)N_EDGES * 4;
    int* bsum = (int*)p;      p += 256 * 4;
    int* boff = (int*)p;      p += 256 * 4;

    const u16* W1t[3] = {Wall, Wall + 32768, Wall + 98304};
    const u16* W2t[3] = {Wall + 163840, Wall + 229376, Wall + 294912};

    const int NBLK = (N_NODES + 255) / 256;  // 196

    hipMemsetAsync(sums, 0, zero_bytes, stream);
    hipMemsetAsync(out_pooled, 0, (size_t)N_GRAPHS * 768 * sizeof(float), stream);

    // CSR build
    count_deg<<<(N_EDGES + 255) / 256, 256, 0, stream>>>(edst, deg, N_EDGES);
    scan_block<<<NBLK, 256, 0, stream>>>(deg, row_start, bsum, N_NODES);
    scan_partials<<<1, 256, 0, stream>>>(bsum, boff, row_start, cursor, NBLK);
    add_offsets<<<NBLK, 256, 0, stream>>>(row_start, cursor, boff, N_NODES);
    fill_csr<<<(N_EDGES + 255) / 256, 256, 0, stream>>>(esrc, edst, cursor, srcs, N_EDGES);

    // all dtype converts in one kernel
    {
        const int n4 = N_NODES * F_IN / 4;  // 1,600,000 float4s
        const int tot = n4 + 360448;
        convert_all<<<(tot + 255) / 256, 256, 0, stream>>>(
            (const float4*)x, (uint2*)H, n4,
            w1[0], w1[1], w1[2], w2[0], w2[1], w2[2], Wall);
    }

    const int AGRID = (N_NODES + 3) / 4;      // 12500 (wave per node)
    const int MGRID = (N_NODES + 63) / 64;    // 782 (fused MLP, 64-row tiles)
    const int PBLK = (N_NODES + 63) / 64;     // 782
    for (int L = 0; L < 3; ++L) {
        float* sumsL = sums + L * 512;
        if (L == 0) {
            aggregate_v2<128><<<AGRID, 256, 0, stream>>>(H, row_start, srcs, Abf, N_NODES);
            mlp_fused<128><<<MGRID, 512, 0, stream>>>(Abf, W1t[L], b1[L], W2t[L], b2[L],
                                                      Mb, sumsL, N_NODES);
        } else {
            aggregate_v2<256><<<AGRID, 256, 0, stream>>>(H, row_start, srcs, Abf, N_NODES);
            mlp_fused<256><<<MGRID, 512, 0, stream>>>(Abf, W1t[L], b1[L], W2t[L], b2[L],
                                                      Mb, sumsL, N_NODES);
        }
        if (L < 2)
            bn_apply_pool<1><<<PBLK, 256, 0, stream>>>(Mb, sumsL, bng[L], bnb[L], batch,
                                                       out_nodes, H, out_pooled, L * 256, N_NODES, 1.0f / N_NODES);
        else
            bn_apply_pool<0><<<PBLK, 256, 0, stream>>>(Mb, sumsL, bng[L], bnb[L], batch,
                                                       out_nodes, H, out_pooled, L * 256, N_NODES, 1.0f / N_NODES);
    }
}

// Round 10
// 695.752 us; speedup vs baseline: 1.0107x; 1.0107x over previous
//
#include <hip/hip_runtime.h>

#define N_NODES 50000
#define N_EDGES 800000
#define F_IN 128
#define DIM 256
#define N_GRAPHS 512
#define BN_EPS 1e-5f

typedef unsigned short u16;
typedef unsigned int u32;
using floatx4 = __attribute__((ext_vector_type(4))) float;
using short8 = __attribute__((ext_vector_type(8))) short;
using half2v = __attribute__((ext_vector_type(2))) _Float16;

#if __has_builtin(__builtin_amdgcn_fdot2)
#define HAS_FDOT2 1
#endif

// ---- fp16 helpers ----
__device__ __forceinline__ u16 f2h(float f) {
    _Float16 h = (_Float16)f;
    return __builtin_bit_cast(u16, h);
}
__device__ __forceinline__ float hlo(u32 u) {
    half2v h = __builtin_bit_cast(half2v, u);
    return (float)h.x;
}
__device__ __forceinline__ float hhi(u32 u) {
    half2v h = __builtin_bit_cast(half2v, u);
    return (float)h.y;
}
__device__ __forceinline__ u32 pack2(float a, float b) {
    half2v h = {(_Float16)a, (_Float16)b};
    return __builtin_bit_cast(u32, h);
}
__device__ __forceinline__ void dacc(u32 w, float& a, float& b) {
#ifdef HAS_FDOT2
    half2v v = __builtin_bit_cast(half2v, w);
    const half2v L = {(_Float16)1.0f, (_Float16)0.0f};
    const half2v Hm = {(_Float16)0.0f, (_Float16)1.0f};
    a = __builtin_amdgcn_fdot2(v, L, a, false);
    b = __builtin_amdgcn_fdot2(v, Hm, b, false);
#else
    a += hlo(w);
    b += hhi(w);
#endif
}
__device__ __forceinline__ void load_lds16(const void* g, void* l) {
    __builtin_amdgcn_global_load_lds((const __attribute__((address_space(1))) void*)g,
                                     (__attribute__((address_space(3))) void*)l, 16, 0, 0);
}

// ---------------- CSR build ----------------

__global__ void count_deg(const int* __restrict__ dst, int* __restrict__ deg, int nE) {
    int e = blockIdx.x * 256 + threadIdx.x;
    if (e < nE) atomicAdd(&deg[dst[e]], 1);
}

__global__ void scan_block(const int* __restrict__ deg, int* __restrict__ row_start,
                           int* __restrict__ bsum, int n) {
    __shared__ int wtot[4];
    int i = blockIdx.x * 256 + threadIdx.x;
    int lane = threadIdx.x & 63, w = threadIdx.x >> 6;
    int v = (i < n) ? deg[i] : 0;
    int s = v;
#pragma unroll
    for (int d = 1; d < 64; d <<= 1) {
        int t = __shfl_up(s, d);
        if (lane >= d) s += t;
    }
    if (lane == 63) wtot[w] = s;
    __syncthreads();
    int off = 0;
#pragma unroll
    for (int k = 0; k < 4; ++k)
        if (k < w) off += wtot[k];
    s += off;
    if (i < n) row_start[i + 1] = s;
    if (threadIdx.x == 255) bsum[blockIdx.x] = s;
}

__global__ void scan_partials(const int* __restrict__ bsum, int* __restrict__ boff,
                              int* __restrict__ row_start, int* __restrict__ cursor, int nb) {
    __shared__ int wtot[4];
    int i = threadIdx.x;
    int lane = i & 63, w = i >> 6;
    int v = (i < nb) ? bsum[i] : 0;
    int s = v;
#pragma unroll
    for (int d = 1; d < 64; d <<= 1) {
        int t = __shfl_up(s, d);
        if (lane >= d) s += t;
    }
    if (lane == 63) wtot[w] = s;
    __syncthreads();
    int off = 0;
#pragma unroll
    for (int k = 0; k < 4; ++k)
        if (k < w) off += wtot[k];
    boff[i] = s + off - v;
    if (i == 0) { row_start[0] = 0; cursor[0] = 0; }
}

__global__ void add_offsets(int* __restrict__ row_start, int* __restrict__ cursor,
                            const int* __restrict__ boff, int n) {
    int i = blockIdx.x * 256 + threadIdx.x;
    if (i < n) {
        int fin = row_start[i + 1] + boff[blockIdx.x];
        row_start[i + 1] = fin;
        cursor[i + 1] = fin;
    }
}

__global__ void fill_csr(const int* __restrict__ src, const int* __restrict__ dst,
                         int* __restrict__ cursor, int* __restrict__ srcs, int nE) {
    int e = blockIdx.x * 256 + threadIdx.x;
    if (e < nE) {
        int p = atomicAdd(&cursor[dst[e]], 1);
        srcs[p] = src[e];
    }
}

// ---------------- one-shot converts ----------------

__global__ void convert_all(const float4* __restrict__ x4, uint2* __restrict__ Hout, int n4,
                            const float* __restrict__ w10, const float* __restrict__ w11,
                            const float* __restrict__ w12, const float* __restrict__ w20,
                            const float* __restrict__ w21, const float* __restrict__ w22,
                            u16* __restrict__ Wall) {
    int i = blockIdx.x * 256 + threadIdx.x;
    if (i < n4) {
        float4 v = x4[i];
        uint2 p;
        p.x = pack2(v.x, v.y);
        p.y = pack2(v.z, v.w);
        Hout[i] = p;
        return;
    }
    int j = i - n4;
    if (j >= 360448) return;
    const float* w;
    int K, base;
    if (j < 32768)       { w = w10; K = 128; base = 0; }
    else if (j < 98304)  { w = w11; K = 256; base = 32768; }
    else if (j < 163840) { w = w12; K = 256; base = 98304; }
    else if (j < 229376) { w = w20; K = 256; base = 163840; }
    else if (j < 294912) { w = w21; K = 256; base = 229376; }
    else                 { w = w22; K = 256; base = 294912; }
    int loc = j - base;
    int nn = loc / K, kk = loc - nn * K;
    Wall[j] = f2h(w[(size_t)kk * 256 + nn]);
}

// ---------------- aggregation: agg = h_i + sum_j h_j, optional fused BN affine ----------------
// One wave per node; NSUB row-groups; uint4 gathers (1KiB/instr), 8 in flight.
// AFFINE=1: input rows are PRE-BN m (f16). Since BN is affine (h = sc*m + sh per column):
//   agg_h = sc * (m_i + sum_j m_j) + (1+deg) * sh   -- exact, applied once in fp32.
// This removes the H buffer write/read between layers entirely.

template <int K, int AFFINE>
__global__ __launch_bounds__(256) void aggregate_v2(
    const u16* __restrict__ h, const int* __restrict__ row_start,
    const int* __restrict__ srcs, u16* __restrict__ outp,
    const float* __restrict__ sums, const float* __restrict__ g,
    const float* __restrict__ bb, float inv_n, int n) {
    constexpr int RW = K / 2;                 // u32 per row (128 or 64)
    constexpr int NSUB = (K == 256) ? 2 : 4;  // rows per gather instruction
    int node = (int)(((size_t)blockIdx.x * blockDim.x + threadIdx.x) >> 6);
    int lane = threadIdx.x & 63;
    if (node >= n) return;
    const u32* hb = (const u32*)h;
    const int sub = lane / (64 / NSUB);       // row-group within the wave
    const int li = lane % (64 / NSUB);        // 16B chunk index within row

    float acc[8];
#pragma unroll
    for (int t = 0; t < 8; ++t) acc[t] = 0.f;
    {
        if (sub == 0) {
            uint4 v = *(const uint4*)(hb + (size_t)node * RW + li * 4);
            dacc(v.x, acc[0], acc[1]);
            dacc(v.y, acc[2], acc[3]);
            dacc(v.z, acc[4], acc[5]);
            dacc(v.w, acc[6], acc[7]);
        }
    }

    int s = row_start[node], e = row_start[node + 1];
    for (int j0 = s; j0 < e; j0 += 64) {
        int myidx = (j0 + lane < e) ? srcs[j0 + lane] : 0;
        int cnt = min(64, e - j0);
        int j = 0;
        for (; j + NSUB * 8 - 1 < cnt; j += NSUB * 8) {
            uint4 gg[8];
#pragma unroll
            for (int q = 0; q < 8; ++q) {
                int sq = __shfl(myidx, j + q * NSUB + sub);
                gg[q] = *(const uint4*)(hb + (size_t)sq * RW + li * 4);
            }
#pragma unroll
            for (int q = 0; q < 8; ++q) {
                dacc(gg[q].x, acc[0], acc[1]);
                dacc(gg[q].y, acc[2], acc[3]);
                dacc(gg[q].z, acc[4], acc[5]);
                dacc(gg[q].w, acc[6], acc[7]);
            }
        }
        for (; j + NSUB * 4 - 1 < cnt; j += NSUB * 4) {
            uint4 gg[4];
#pragma unroll
            for (int q = 0; q < 4; ++q) {
                int sq = __shfl(myidx, j + q * NSUB + sub);
                gg[q] = *(const uint4*)(hb + (size_t)sq * RW + li * 4);
            }
#pragma unroll
            for (int q = 0; q < 4; ++q) {
                dacc(gg[q].x, acc[0], acc[1]);
                dacc(gg[q].y, acc[2], acc[3]);
                dacc(gg[q].z, acc[4], acc[5]);
                dacc(gg[q].w, acc[6], acc[7]);
            }
        }
        for (; j < cnt; j += NSUB) {
            int idx = j + sub;
            bool valid = idx < cnt;
            int sq = __shfl(myidx, valid ? idx : j);
            if (valid) {
                uint4 gg = *(const uint4*)(hb + (size_t)sq * RW + li * 4);
                dacc(gg.x, acc[0], acc[1]);
                dacc(gg.y, acc[2], acc[3]);
                dacc(gg.z, acc[4], acc[5]);
                dacc(gg.w, acc[6], acc[7]);
            }
        }
    }

    if (NSUB == 4) {
#pragma unroll
        for (int t = 0; t < 8; ++t) acc[t] += __shfl_xor(acc[t], 16);
    }
#pragma unroll
    for (int t = 0; t < 8; ++t) acc[t] += __shfl_xor(acc[t], 32);

    if (sub == 0) {
        if (AFFINE) {
            // lane li owns cols [8*li, 8*li+8)
            int c = li * 8;
            float degp1 = (float)(e - s + 1);
            float4 s1a = *(const float4*)(sums + c), s1b = *(const float4*)(sums + c + 4);
            float4 s2a = *(const float4*)(sums + 256 + c), s2b = *(const float4*)(sums + 256 + c + 4);
            float4 g4a = *(const float4*)(g + c), g4b = *(const float4*)(g + c + 4);
            float4 b4a = *(const float4*)(bb + c), b4b = *(const float4*)(bb + c + 4);
            float mu[8] = {s1a.x, s1a.y, s1a.z, s1a.w, s1b.x, s1b.y, s1b.z, s1b.w};
            float q2[8] = {s2a.x, s2a.y, s2a.z, s2a.w, s2b.x, s2b.y, s2b.z, s2b.w};
            float gv[8] = {g4a.x, g4a.y, g4a.z, g4a.w, g4b.x, g4b.y, g4b.z, g4b.w};
            float bv[8] = {b4a.x, b4a.y, b4a.z, b4a.w, b4b.x, b4b.y, b4b.z, b4b.w};
#pragma unroll
            for (int t = 0; t < 8; ++t) {
                float m = mu[t] * inv_n;
                float sc = gv[t] / sqrtf(q2[t] * inv_n - m * m + BN_EPS);
                float sh = bv[t] - m * sc;
                acc[t] = sc * acc[t] + degp1 * sh;
            }
        }
        uint4 o;
        o.x = pack2(acc[0], acc[1]);
        o.y = pack2(acc[2], acc[3]);
        o.z = pack2(acc[4], acc[5]);
        o.w = pack2(acc[6], acc[7]);
        *(uint4*)((u32*)outp + (size_t)node * RW + li * 4) = o;
    }
}

// ---------------- fused MLP: m = relu(relu(A@W1+b1)@W2+b2), f16 out + BN sums ----------------
// 64-row tile, 512 threads = 8 waves (2m x 4n), wave tile 32x64.
// K-step 64: 16 MFMA + 12 ds_read_b128 per barrier-pair (2x round 8's ratio).
// As/Bs are [rows][64] with 16B-chunk XOR-swizzle (chunk ^= row&7). Since global_load_lds
// writes linearly (wave-uniform base + lane*16), the swizzle is applied by permuting the
// GLOBAL source chunk per lane (Guideline 21); reads apply the same XOR -> conflict-free
// (old 64B-row layout was an 8-way bank conflict on every fragment read).
// LDS: As 8KB + Bs 32KB + Ts 32KB = 72KB -> 2 blocks/CU.

template <int K1>
__global__ __launch_bounds__(512, 2) void mlp_fused(
    const u16* __restrict__ A, const u16* __restrict__ B1t, const float* __restrict__ b1,
    const u16* __restrict__ B2t, const float* __restrict__ b2,
    u16* __restrict__ Cout, float* __restrict__ sums, int M) {
    __shared__ u16 As[64 * 64];    // 8 KB
    __shared__ u16 Bs[256 * 64];   // 32 KB
    __shared__ u16 Ts[64 * 256];   // 32 KB
    const int tid = threadIdx.x;
    const int w = tid >> 6, lane = tid & 63;
    const int wm = w >> 2, wn = w & 3;
    const int r = lane & 15, rg = lane >> 4;
    const int bm = blockIdx.x * 64;

    floatx4 acc[2][4];
#pragma unroll
    for (int i = 0; i < 2; ++i)
#pragma unroll
        for (int j = 0; j < 4; ++j) acc[i][j] = (floatx4){0.f, 0.f, 0.f, 0.f};

    // ---- phase 1: T = relu(A @ W1^T + b1) -> Ts ----
    for (int k0 = 0; k0 < K1; k0 += 64) {
        __syncthreads();
        {
            // As: row = tid>>3 (64 rows), source chunk pre-swizzled
            int arow = bm + (tid >> 3);
            if (arow >= M) arow = M - 1;
            int swz = (tid & 7) ^ ((tid >> 3) & 7);
            load_lds16(A + (size_t)arow * K1 + k0 + swz * 8, As + w * 512);
        }
#pragma unroll
        for (int q = 0; q < 4; ++q) {
            int i = q * 512 + tid;
            int nrow = i >> 3;
            int swz = (i & 7) ^ (nrow & 7);
            load_lds16(B1t + (size_t)nrow * K1 + k0 + swz * 8, Bs + q * 4096 + w * 512);
        }
        __syncthreads();
        short8 a[2][2], b[4][2];
#pragma unroll
        for (int mi = 0; mi < 2; ++mi) {
            int row = wm * 32 + mi * 16 + r;
#pragma unroll
            for (int kk = 0; kk < 2; ++kk) {
                int ck = (kk * 4 + rg) ^ (row & 7);
                a[mi][kk] = *(const short8*)(As + row * 64 + ck * 8);
            }
        }
#pragma unroll
        for (int ni = 0; ni < 4; ++ni) {
            int row = wn * 64 + ni * 16 + r;
#pragma unroll
            for (int kk = 0; kk < 2; ++kk) {
                int ck = (kk * 4 + rg) ^ (row & 7);
                b[ni][kk] = *(const short8*)(Bs + row * 64 + ck * 8);
            }
        }
#pragma unroll
        for (int kk = 0; kk < 2; ++kk)
#pragma unroll
            for (int mi = 0; mi < 2; ++mi)
#pragma unroll
                for (int ni = 0; ni < 4; ++ni)
                    acc[mi][ni] = __builtin_amdgcn_mfma_f32_16x16x32_f16(a[mi][kk], b[ni][kk], acc[mi][ni], 0, 0, 0);
    }
    // epilogue 1: relu+bias, f16-quantize, swizzled store into Ts (chunk of 32 per row)
#pragma unroll
    for (int ni = 0; ni < 4; ++ni) {
        int col = wn * 64 + ni * 16 + r;
        float bv = b1[col];
#pragma unroll
        for (int mi = 0; mi < 2; ++mi)
#pragma unroll
            for (int rr = 0; rr < 4; ++rr) {
                int lrow = wm * 32 + mi * 16 + rg * 4 + rr;
                float v = fmaxf(acc[mi][ni][rr] + bv, 0.f);
                int chunk = (col >> 3) ^ (lrow & 7);
                *(u16*)((char*)Ts + lrow * 512 + chunk * 16 + (col & 7) * 2) = f2h(v);
            }
#pragma unroll
        for (int mi = 0; mi < 2; ++mi) acc[mi][ni] = (floatx4){0.f, 0.f, 0.f, 0.f};
    }

    // ---- phase 2: m = relu(T @ W2^T + b2) ----
    for (int k0 = 0; k0 < 256; k0 += 64) {
        __syncthreads();  // Ts ready (1st iter) / Bs consumed (later)
#pragma unroll
        for (int q = 0; q < 4; ++q) {
            int i = q * 512 + tid;
            int nrow = i >> 3;
            int swz = (i & 7) ^ (nrow & 7);
            load_lds16(B2t + (size_t)nrow * 256 + k0 + swz * 8, Bs + q * 4096 + w * 512);
        }
        __syncthreads();
        short8 a[2][2], b[4][2];
#pragma unroll
        for (int mi = 0; mi < 2; ++mi) {
            int lrow = wm * 32 + mi * 16 + r;
#pragma unroll
            for (int kk = 0; kk < 2; ++kk) {
                int ck = ((k0 >> 3) + kk * 4 + rg) ^ (lrow & 7);
                a[mi][kk] = *(const short8*)((const char*)Ts + lrow * 512 + ck * 16);
            }
        }
#pragma unroll
        for (int ni = 0; ni < 4; ++ni) {
            int row = wn * 64 + ni * 16 + r;
#pragma unroll
            for (int kk = 0; kk < 2; ++kk) {
                int ck = (kk * 4 + rg) ^ (row & 7);
                b[ni][kk] = *(const short8*)(Bs + row * 64 + ck * 8);
            }
        }
#pragma unroll
        for (int kk = 0; kk < 2; ++kk)
#pragma unroll
            for (int mi = 0; mi < 2; ++mi)
#pragma unroll
                for (int ni = 0; ni < 4; ++ni)
                    acc[mi][ni] = __builtin_amdgcn_mfma_f32_16x16x32_f16(a[mi][kk], b[ni][kk], acc[mi][ni], 0, 0, 0);
    }

    // epilogue 2: relu+bias, f16 out (stats on quantized values), fused BN partial sums
#pragma unroll
    for (int ni = 0; ni < 4; ++ni) {
        int col = wn * 64 + ni * 16 + r;
        float bv = b2[col];
        float s = 0.f, s2 = 0.f;
#pragma unroll
        for (int mi = 0; mi < 2; ++mi)
#pragma unroll
            for (int rr = 0; rr < 4; ++rr) {
                int row = bm + wm * 32 + mi * 16 + rg * 4 + rr;
                if (row < M) {
                    float v = fmaxf(acc[mi][ni][rr] + bv, 0.f);
                    u16 qb = f2h(v);
                    float vq = hlo((u32)qb);
                    Cout[(size_t)row * 256 + col] = qb;
                    s += vq;
                    s2 += vq * vq;
                }
            }
        s += __shfl_xor(s, 16);
        s += __shfl_xor(s, 32);
        s2 += __shfl_xor(s2, 16);
        s2 += __shfl_xor(s2, 32);
        if (rg == 0) {
            atomicAdd(&sums[col], s);
            atomicAdd(&sums[256 + col], s2);
        }
    }
}

// ---------------- BN finalize + fp32 out_nodes + per-graph pooling (no H write) ----------------

__global__ void bn_pool(const u16* __restrict__ Mb, const float* __restrict__ sums,
                        const float* __restrict__ g, const float* __restrict__ bb,
                        const int* __restrict__ batch, float* __restrict__ out_nodes,
                        float* __restrict__ pooled, int col_off, int n, float inv_n) {
    int w = threadIdx.x >> 6, lane = threadIdx.x & 63;
    int base = blockIdx.x * 64 + w * 16;
    if (base >= n) return;
    int c4 = lane << 2;
    float4 s1 = *(const float4*)(sums + c4);
    float4 s2 = *(const float4*)(sums + 256 + c4);
    float4 g4 = *(const float4*)(g + c4);
    float4 b4 = *(const float4*)(bb + c4);
    float4 sc, sh;
    {
        float mux = s1.x * inv_n, muy = s1.y * inv_n, muz = s1.z * inv_n, muw = s1.w * inv_n;
        sc.x = g4.x / sqrtf(s2.x * inv_n - mux * mux + BN_EPS);
        sc.y = g4.y / sqrtf(s2.y * inv_n - muy * muy + BN_EPS);
        sc.z = g4.z / sqrtf(s2.z * inv_n - muz * muz + BN_EPS);
        sc.w = g4.w / sqrtf(s2.w * inv_n - muw * muw + BN_EPS);
        sh.x = b4.x - mux * sc.x;
        sh.y = b4.y - muy * sc.y;
        sh.z = b4.z - muz * sc.z;
        sh.w = b4.w - muw * sc.w;
    }
    float4 acc = make_float4(0.f, 0.f, 0.f, 0.f);
    int gcur = -1;
    int end = min(base + 16, n);
    for (int row = base; row < end; ++row) {
        uint2 pk = *(const uint2*)(Mb + (size_t)row * 256 + c4);
        float4 o;
        o.x = fmaf(hlo(pk.x), sc.x, sh.x);
        o.y = fmaf(hhi(pk.x), sc.y, sh.y);
        o.z = fmaf(hlo(pk.y), sc.z, sh.z);
        o.w = fmaf(hhi(pk.y), sc.w, sh.w);
        floatx4 ov = {o.x, o.y, o.z, o.w};
        __builtin_nontemporal_store(ov, (floatx4*)(out_nodes + (size_t)row * 768 + col_off + c4));
        int gg = batch[row];
        if (gg != gcur) {
            if (gcur >= 0) {
                float* pp = pooled + (size_t)gcur * 768 + col_off + c4;
                atomicAdd(pp + 0, acc.x);
                atomicAdd(pp + 1, acc.y);
                atomicAdd(pp + 2, acc.z);
                atomicAdd(pp + 3, acc.w);
            }
            gcur = gg;
            acc = o;
        } else {
            acc.x += o.x; acc.y += o.y; acc.z += o.z; acc.w += o.w;
        }
    }
    if (gcur >= 0) {
        float* pp = pooled + (size_t)gcur * 768 + col_off + c4;
        atomicAdd(pp + 0, acc.x);
        atomicAdd(pp + 1, acc.y);
        atomicAdd(pp + 2, acc.z);
        atomicAdd(pp + 3, acc.w);
    }
}

// ---------------- launch ----------------

extern "C" void kernel_launch(void* const* d_in, const int* in_sizes, int n_in,
                              void* d_out, int out_size, void* d_ws, size_t ws_size,
                              hipStream_t stream) {
    const float* x = (const float*)d_in[0];
    const int* esrc = (const int*)d_in[1];
    const int* edst = esrc + N_EDGES;
    const int* batch = (const int*)d_in[2];

    const float* w1[3] = {(const float*)d_in[3], (const float*)d_in[9], (const float*)d_in[15]};
    const float* b1[3] = {(const float*)d_in[4], (const float*)d_in[10], (const float*)d_in[16]};
    const float* w2[3] = {(const float*)d_in[5], (const float*)d_in[11], (const float*)d_in[17]};
    const float* b2[3] = {(const float*)d_in[6], (const float*)d_in[12], (const float*)d_in[18]};
    const float* bng[3] = {(const float*)d_in[7], (const float*)d_in[13], (const float*)d_in[19]};
    const float* bnb[3] = {(const float*)d_in[8], (const float*)d_in[14], (const float*)d_in[20]};

    float* out_pooled = (float*)d_out;
    float* out_nodes = (float*)d_out + (size_t)N_GRAPHS * 768;

    char* p = (char*)d_ws;
    u16* Abf = (u16*)p; p += (size_t)N_NODES * 256 * 2;  // aggregate out (MLP input)
    u16* Mb = (u16*)p;  p += (size_t)N_NODES * 256 * 2;  // MLP m out (pre-BN)
    u16* H = (u16*)p;   p += (size_t)N_NODES * 256 * 2;  // f16(x) for layer 0 only
    u16* Wall = (u16*)p; p += (size_t)360448 * 2;        // all transposed weights
    float* sums = (float*)p; p += 3 * 512 * 4;
    int* deg = (int*)p;      p += (size_t)N_NODES * 4;
    const size_t zero_bytes = 3 * 512 * 4 + (size_t)N_NODES * 4;
    int* row_start = (int*)p; p += (size_t)(N_NODES + 1) * 4;
    int* cursor = (int*)p;    p += (size_t)(N_NODES + 1) * 4;
    int* srcs = (int*)p;      p += (size_t)N_EDGES * 4;
    int* bsum = (int*)p;      p += 256 * 4;
    int* boff = (int*)p;      p += 256 * 4;

    const u16* W1t[3] = {Wall, Wall + 32768, Wall + 98304};
    const u16* W2t[3] = {Wall + 163840, Wall + 229376, Wall + 294912};

    const int NBLK = (N_NODES + 255) / 256;  // 196

    hipMemsetAsync(sums, 0, zero_bytes, stream);
    hipMemsetAsync(out_pooled, 0, (size_t)N_GRAPHS * 768 * sizeof(float), stream);

    // CSR build
    count_deg<<<(N_EDGES + 255) / 256, 256, 0, stream>>>(edst, deg, N_EDGES);
    scan_block<<<NBLK, 256, 0, stream>>>(deg, row_start, bsum, N_NODES);
    scan_partials<<<1, 256, 0, stream>>>(bsum, boff, row_start, cursor, NBLK);
    add_offsets<<<NBLK, 256, 0, stream>>>(row_start, cursor, boff, N_NODES);
    fill_csr<<<(N_EDGES + 255) / 256, 256, 0, stream>>>(esrc, edst, cursor, srcs, N_EDGES);

    {
        const int n4 = N_NODES * F_IN / 4;
        const int tot = n4 + 360448;
        convert_all<<<(tot + 255) / 256, 256, 0, stream>>>(
            (const float4*)x, (uint2*)H, n4,
            w1[0], w1[1], w1[2], w2[0], w2[1], w2[2], Wall);
    }

    const int AGRID = (N_NODES + 3) / 4;      // wave per node
    const int MGRID = (N_NODES + 63) / 64;
    const int PBLK = (N_NODES + 63) / 64;
    const float inv_n = 1.0f / N_NODES;

    // L0
    aggregate_v2<128, 0><<<AGRID, 256, 0, stream>>>(H, row_start, srcs, Abf,
                                                    nullptr, nullptr, nullptr, inv_n, N_NODES);
    mlp_fused<128><<<MGRID, 512, 0, stream>>>(Abf, W1t[0], b1[0], W2t[0], b2[0], Mb, sums, N_NODES);
    // L1 (aggregate applies BN-0 affine inline from Mb)
    aggregate_v2<256, 1><<<AGRID, 256, 0, stream>>>(Mb, row_start, srcs, Abf,
                                                    sums, bng[0], bnb[0], inv_n, N_NODES);
    bn_pool<<<PBLK, 256, 0, stream>>>(Mb, sums, bng[0], bnb[0], batch, out_nodes, out_pooled,
                                      0, N_NODES, inv_n);
    mlp_fused<256><<<MGRID, 512, 0, stream>>>(Abf, W1t[1], b1[1], W2t[1], b2[1], Mb, sums + 512, N_NODES);
    // L2
    aggregate_v2<256, 1><<<AGRID, 256, 0, stream>>>(Mb, row_start, srcs, Abf,
                                                    sums + 512, bng[1], bnb[1], inv_n, N_NODES);
    bn_pool<<<PBLK, 256, 0, stream>>>(Mb, sums + 512, bng[1], bnb[1], batch, out_nodes, out_pooled,
                                      256, N_NODES, inv_n);
    mlp_fused<256><<<MGRID, 512, 0, stream>>>(Abf, W1t[2], b1[2], W2t[2], b2[2], Mb, sums + 1024, N_NODES);
    // final output pass
    bn_pool<<<PBLK, 256, 0, stream>>>(Mb, sums + 1024, bng[2], bnb[2], batch, out_nodes, out_pooled,
                                      512, N_NODES, inv_n);
}

// Round 11
// 653.371 us; speedup vs baseline: 1.0763x; 1.0649x over previous
//
#include <hip/hip_runtime.h>

#define N_NODES 50000
#define N_EDGES 800000
#define F_IN 128
#define DIM 256
#define N_GRAPHS 512
#define BN_EPS 1e-5f

typedef unsigned short u16;
typedef unsigned int u32;
using floatx4 = __attribute__((ext_vector_type(4))) float;
using short8 = __attribute__((ext_vector_type(8))) short;
using half2v = __attribute__((ext_vector_type(2))) _Float16;

#if __has_builtin(__builtin_amdgcn_fdot2)
#define HAS_FDOT2 1
#endif

// ---- fp16 helpers ----
__device__ __forceinline__ u16 f2h(float f) {
    _Float16 h = (_Float16)f;
    return __builtin_bit_cast(u16, h);
}
__device__ __forceinline__ float hlo(u32 u) {
    half2v h = __builtin_bit_cast(half2v, u);
    return (float)h.x;
}
__device__ __forceinline__ float hhi(u32 u) {
    half2v h = __builtin_bit_cast(half2v, u);
    return (float)h.y;
}
__device__ __forceinline__ u32 pack2(float a, float b) {
    half2v h = {(_Float16)a, (_Float16)b};
    return __builtin_bit_cast(u32, h);
}
__device__ __forceinline__ void dacc(u32 w, float& a, float& b) {
#ifdef HAS_FDOT2
    half2v v = __builtin_bit_cast(half2v, w);
    const half2v L = {(_Float16)1.0f, (_Float16)0.0f};
    const half2v Hm = {(_Float16)0.0f, (_Float16)1.0f};
    a = __builtin_amdgcn_fdot2(v, L, a, false);
    b = __builtin_amdgcn_fdot2(v, Hm, b, false);
#else
    a += hlo(w);
    b += hhi(w);
#endif
}
__device__ __forceinline__ void load_lds16(const void* g, void* l) {
    __builtin_amdgcn_global_load_lds((const __attribute__((address_space(1))) void*)g,
                                     (__attribute__((address_space(3))) void*)l, 16, 0, 0);
}

// ---------------- CSR build ----------------

__global__ void count_deg(const int* __restrict__ dst, int* __restrict__ deg, int nE) {
    int e = blockIdx.x * 256 + threadIdx.x;
    if (e < nE) atomicAdd(&deg[dst[e]], 1);
}

__global__ void scan_block(const int* __restrict__ deg, int* __restrict__ row_start,
                           int* __restrict__ bsum, int n) {
    __shared__ int wtot[4];
    int i = blockIdx.x * 256 + threadIdx.x;
    int lane = threadIdx.x & 63, w = threadIdx.x >> 6;
    int v = (i < n) ? deg[i] : 0;
    int s = v;
#pragma unroll
    for (int d = 1; d < 64; d <<= 1) {
        int t = __shfl_up(s, d);
        if (lane >= d) s += t;
    }
    if (lane == 63) wtot[w] = s;
    __syncthreads();
    int off = 0;
#pragma unroll
    for (int k = 0; k < 4; ++k)
        if (k < w) off += wtot[k];
    s += off;
    if (i < n) row_start[i + 1] = s;
    if (threadIdx.x == 255) bsum[blockIdx.x] = s;
}

__global__ void scan_partials(const int* __restrict__ bsum, int* __restrict__ boff,
                              int* __restrict__ row_start, int* __restrict__ cursor, int nb) {
    __shared__ int wtot[4];
    int i = threadIdx.x;
    int lane = i & 63, w = i >> 6;
    int v = (i < nb) ? bsum[i] : 0;
    int s = v;
#pragma unroll
    for (int d = 1; d < 64; d <<= 1) {
        int t = __shfl_up(s, d);
        if (lane >= d) s += t;
    }
    if (lane == 63) wtot[w] = s;
    __syncthreads();
    int off = 0;
#pragma unroll
    for (int k = 0; k < 4; ++k)
        if (k < w) off += wtot[k];
    boff[i] = s + off - v;
    if (i == 0) { row_start[0] = 0; cursor[0] = 0; }
}

__global__ void add_offsets(int* __restrict__ row_start, int* __restrict__ cursor,
                            const int* __restrict__ boff, int n) {
    int i = blockIdx.x * 256 + threadIdx.x;
    if (i < n) {
        int fin = row_start[i + 1] + boff[blockIdx.x];
        row_start[i + 1] = fin;
        cursor[i + 1] = fin;
    }
}

__global__ void fill_csr(const int* __restrict__ src, const int* __restrict__ dst,
                         int* __restrict__ cursor, int* __restrict__ srcs, int nE) {
    int e = blockIdx.x * 256 + threadIdx.x;
    if (e < nE) {
        int p = atomicAdd(&cursor[dst[e]], 1);
        srcs[p] = src[e];
    }
}

// ---------------- one-shot converts ----------------

__global__ void convert_all(const float4* __restrict__ x4, uint2* __restrict__ Hout, int n4,
                            const float* __restrict__ w10, const float* __restrict__ w11,
                            const float* __restrict__ w12, const float* __restrict__ w20,
                            const float* __restrict__ w21, const float* __restrict__ w22,
                            u16* __restrict__ Wall) {
    int i = blockIdx.x * 256 + threadIdx.x;
    if (i < n4) {
        float4 v = x4[i];
        uint2 p;
        p.x = pack2(v.x, v.y);
        p.y = pack2(v.z, v.w);
        Hout[i] = p;
        return;
    }
    int j = i - n4;
    if (j >= 360448) return;
    const float* w;
    int K, base;
    if (j < 32768)       { w = w10; K = 128; base = 0; }
    else if (j < 98304)  { w = w11; K = 256; base = 32768; }
    else if (j < 163840) { w = w12; K = 256; base = 98304; }
    else if (j < 229376) { w = w20; K = 256; base = 163840; }
    else if (j < 294912) { w = w21; K = 256; base = 229376; }
    else                 { w = w22; K = 256; base = 294912; }
    int loc = j - base;
    int nn = loc / K, kk = loc - nn * K;
    Wall[j] = f2h(w[(size_t)kk * 256 + nn]);
}

// ---------------- aggregation: agg = h_i + sum_j h_j, optional fused BN affine ----------------
// One wave per node; NSUB row-groups; uint4 gathers (1KiB/instr), 8 in flight.
// AFFINE=1: input rows are PRE-BN m (f16); BN affine applied once in fp32 after the sum.

template <int K, int AFFINE>
__global__ __launch_bounds__(256) void aggregate_v2(
    const u16* __restrict__ h, const int* __restrict__ row_start,
    const int* __restrict__ srcs, u16* __restrict__ outp,
    const float* __restrict__ sums, const float* __restrict__ g,
    const float* __restrict__ bb, float inv_n, int n) {
    constexpr int RW = K / 2;                 // u32 per row (128 or 64)
    constexpr int NSUB = (K == 256) ? 2 : 4;  // rows per gather instruction
    int node = (int)(((size_t)blockIdx.x * blockDim.x + threadIdx.x) >> 6);
    int lane = threadIdx.x & 63;
    if (node >= n) return;
    const u32* hb = (const u32*)h;
    const int sub = lane / (64 / NSUB);       // row-group within the wave
    const int li = lane % (64 / NSUB);        // 16B chunk index within row

    float acc[8];
#pragma unroll
    for (int t = 0; t < 8; ++t) acc[t] = 0.f;
    {
        if (sub == 0) {
            uint4 v = *(const uint4*)(hb + (size_t)node * RW + li * 4);
            dacc(v.x, acc[0], acc[1]);
            dacc(v.y, acc[2], acc[3]);
            dacc(v.z, acc[4], acc[5]);
            dacc(v.w, acc[6], acc[7]);
        }
    }

    int s = row_start[node], e = row_start[node + 1];
    for (int j0 = s; j0 < e; j0 += 64) {
        int myidx = (j0 + lane < e) ? srcs[j0 + lane] : 0;
        int cnt = min(64, e - j0);
        int j = 0;
        for (; j + NSUB * 8 - 1 < cnt; j += NSUB * 8) {
            uint4 gg[8];
#pragma unroll
            for (int q = 0; q < 8; ++q) {
                int sq = __shfl(myidx, j + q * NSUB + sub);
                gg[q] = *(const uint4*)(hb + (size_t)sq * RW + li * 4);
            }
#pragma unroll
            for (int q = 0; q < 8; ++q) {
                dacc(gg[q].x, acc[0], acc[1]);
                dacc(gg[q].y, acc[2], acc[3]);
                dacc(gg[q].z, acc[4], acc[5]);
                dacc(gg[q].w, acc[6], acc[7]);
            }
        }
        for (; j + NSUB * 4 - 1 < cnt; j += NSUB * 4) {
            uint4 gg[4];
#pragma unroll
            for (int q = 0; q < 4; ++q) {
                int sq = __shfl(myidx, j + q * NSUB + sub);
                gg[q] = *(const uint4*)(hb + (size_t)sq * RW + li * 4);
            }
#pragma unroll
            for (int q = 0; q < 4; ++q) {
                dacc(gg[q].x, acc[0], acc[1]);
                dacc(gg[q].y, acc[2], acc[3]);
                dacc(gg[q].z, acc[4], acc[5]);
                dacc(gg[q].w, acc[6], acc[7]);
            }
        }
        for (; j < cnt; j += NSUB) {
            int idx = j + sub;
            bool valid = idx < cnt;
            int sq = __shfl(myidx, valid ? idx : j);
            if (valid) {
                uint4 gg = *(const uint4*)(hb + (size_t)sq * RW + li * 4);
                dacc(gg.x, acc[0], acc[1]);
                dacc(gg.y, acc[2], acc[3]);
                dacc(gg.z, acc[4], acc[5]);
                dacc(gg.w, acc[6], acc[7]);
            }
        }
    }

    if (NSUB == 4) {
#pragma unroll
        for (int t = 0; t < 8; ++t) acc[t] += __shfl_xor(acc[t], 16);
    }
#pragma unroll
    for (int t = 0; t < 8; ++t) acc[t] += __shfl_xor(acc[t], 32);

    if (sub == 0) {
        if (AFFINE) {
            int c = li * 8;
            float degp1 = (float)(e - s + 1);
            float4 s1a = *(const float4*)(sums + c), s1b = *(const float4*)(sums + c + 4);
            float4 s2a = *(const float4*)(sums + 256 + c), s2b = *(const float4*)(sums + 256 + c + 4);
            float4 g4a = *(const float4*)(g + c), g4b = *(const float4*)(g + c + 4);
            float4 b4a = *(const float4*)(bb + c), b4b = *(const float4*)(bb + c + 4);
            float mu[8] = {s1a.x, s1a.y, s1a.z, s1a.w, s1b.x, s1b.y, s1b.z, s1b.w};
            float q2[8] = {s2a.x, s2a.y, s2a.z, s2a.w, s2b.x, s2b.y, s2b.z, s2b.w};
            float gv[8] = {g4a.x, g4a.y, g4a.z, g4a.w, g4b.x, g4b.y, g4b.z, g4b.w};
            float bv[8] = {b4a.x, b4a.y, b4a.z, b4a.w, b4b.x, b4b.y, b4b.z, b4b.w};
#pragma unroll
            for (int t = 0; t < 8; ++t) {
                float m = mu[t] * inv_n;
                float sc = gv[t] / sqrtf(q2[t] * inv_n - m * m + BN_EPS);
                float sh = bv[t] - m * sc;
                acc[t] = sc * acc[t] + degp1 * sh;
            }
        }
        uint4 o;
        o.x = pack2(acc[0], acc[1]);
        o.y = pack2(acc[2], acc[3]);
        o.z = pack2(acc[4], acc[5]);
        o.w = pack2(acc[6], acc[7]);
        *(uint4*)((u32*)outp + (size_t)node * RW + li * 4) = o;
    }
}

// ---------------- merged MLP + previous-layer BN/pool (heterogeneous blocks) ----------------
// blockIdx < nBn           : bn_pool role for layer L-1 (reads Mprev; 8 waves x 16 rows).
//                            Placed FIRST so these memory-bound blocks dispatch early and
//                            run under the shadow of the MFMA-bound MLP blocks.
// blockIdx >= nBn          : mlp role for layer L (R10's K-step-64, swizzled, 64-row tile).
// Safe because Mb ping-pongs: BN reads Mb[L-1&1], MLP writes Mb[L&1] (disjoint buffers).
// Branch is block-uniform; the bn role returns before any __syncthreads.

template <int K1>
__global__ __launch_bounds__(512, 2) void mlp_bn(
    const u16* __restrict__ A, const u16* __restrict__ B1t, const float* __restrict__ b1,
    const u16* __restrict__ B2t, const float* __restrict__ b2,
    u16* __restrict__ Cout, float* __restrict__ sums_out, int M, int nBn,
    const u16* __restrict__ Mprev, const float* __restrict__ sums_in,
    const float* __restrict__ g, const float* __restrict__ bb,
    const int* __restrict__ batch, float* __restrict__ out_nodes,
    float* __restrict__ pooled, int col_off, float inv_n) {
    __shared__ u16 As[64 * 64];    // 8 KB
    __shared__ u16 Bs[256 * 64];   // 32 KB
    __shared__ u16 Ts[64 * 256];   // 32 KB
    const int tid = threadIdx.x;
    const int w = tid >> 6, lane = tid & 63;

    if ((int)blockIdx.x < nBn) {
        // ---- bn_pool role: 512 threads = 8 waves x 16 rows = 128 rows/block ----
        int base = blockIdx.x * 128 + w * 16;
        if (base >= M) return;
        int c4 = lane << 2;
        float4 s1 = *(const float4*)(sums_in + c4);
        float4 s2 = *(const float4*)(sums_in + 256 + c4);
        float4 g4 = *(const float4*)(g + c4);
        float4 b4 = *(const float4*)(bb + c4);
        float4 sc, sh;
        {
            float mux = s1.x * inv_n, muy = s1.y * inv_n, muz = s1.z * inv_n, muw = s1.w * inv_n;
            sc.x = g4.x / sqrtf(s2.x * inv_n - mux * mux + BN_EPS);
            sc.y = g4.y / sqrtf(s2.y * inv_n - muy * muy + BN_EPS);
            sc.z = g4.z / sqrtf(s2.z * inv_n - muz * muz + BN_EPS);
            sc.w = g4.w / sqrtf(s2.w * inv_n - muw * muw + BN_EPS);
            sh.x = b4.x - mux * sc.x;
            sh.y = b4.y - muy * sc.y;
            sh.z = b4.z - muz * sc.z;
            sh.w = b4.w - muw * sc.w;
        }
        float4 acc = make_float4(0.f, 0.f, 0.f, 0.f);
        int gcur = -1;
        int end = min(base + 16, M);
        for (int row = base; row < end; ++row) {
            uint2 pk = *(const uint2*)(Mprev + (size_t)row * 256 + c4);
            float4 o;
            o.x = fmaf(hlo(pk.x), sc.x, sh.x);
            o.y = fmaf(hhi(pk.x), sc.y, sh.y);
            o.z = fmaf(hlo(pk.y), sc.z, sh.z);
            o.w = fmaf(hhi(pk.y), sc.w, sh.w);
            floatx4 ov = {o.x, o.y, o.z, o.w};
            __builtin_nontemporal_store(ov, (floatx4*)(out_nodes + (size_t)row * 768 + col_off + c4));
            int gg = batch[row];
            if (gg != gcur) {
                if (gcur >= 0) {
                    float* pp = pooled + (size_t)gcur * 768 + col_off + c4;
                    atomicAdd(pp + 0, acc.x);
                    atomicAdd(pp + 1, acc.y);
                    atomicAdd(pp + 2, acc.z);
                    atomicAdd(pp + 3, acc.w);
                }
                gcur = gg;
                acc = o;
            } else {
                acc.x += o.x; acc.y += o.y; acc.z += o.z; acc.w += o.w;
            }
        }
        if (gcur >= 0) {
            float* pp = pooled + (size_t)gcur * 768 + col_off + c4;
            atomicAdd(pp + 0, acc.x);
            atomicAdd(pp + 1, acc.y);
            atomicAdd(pp + 2, acc.z);
            atomicAdd(pp + 3, acc.w);
        }
        return;
    }

    // ---- mlp role ----
    const int wm = w >> 2, wn = w & 3;
    const int r = lane & 15, rg = lane >> 4;
    const int bm = (blockIdx.x - nBn) * 64;

    floatx4 acc[2][4];
#pragma unroll
    for (int i = 0; i < 2; ++i)
#pragma unroll
        for (int j = 0; j < 4; ++j) acc[i][j] = (floatx4){0.f, 0.f, 0.f, 0.f};

    // phase 1: T = relu(A @ W1^T + b1) -> Ts
    for (int k0 = 0; k0 < K1; k0 += 64) {
        __syncthreads();
        {
            int arow = bm + (tid >> 3);
            if (arow >= M) arow = M - 1;
            int swz = (tid & 7) ^ ((tid >> 3) & 7);
            load_lds16(A + (size_t)arow * K1 + k0 + swz * 8, As + w * 512);
        }
#pragma unroll
        for (int q = 0; q < 4; ++q) {
            int i = q * 512 + tid;
            int nrow = i >> 3;
            int swz = (i & 7) ^ (nrow & 7);
            load_lds16(B1t + (size_t)nrow * K1 + k0 + swz * 8, Bs + q * 4096 + w * 512);
        }
        __syncthreads();
        short8 a[2][2], b[4][2];
#pragma unroll
        for (int mi = 0; mi < 2; ++mi) {
            int row = wm * 32 + mi * 16 + r;
#pragma unroll
            for (int kk = 0; kk < 2; ++kk) {
                int ck = (kk * 4 + rg) ^ (row & 7);
                a[mi][kk] = *(const short8*)(As + row * 64 + ck * 8);
            }
        }
#pragma unroll
        for (int ni = 0; ni < 4; ++ni) {
            int row = wn * 64 + ni * 16 + r;
#pragma unroll
            for (int kk = 0; kk < 2; ++kk) {
                int ck = (kk * 4 + rg) ^ (row & 7);
                b[ni][kk] = *(const short8*)(Bs + row * 64 + ck * 8);
            }
        }
#pragma unroll
        for (int kk = 0; kk < 2; ++kk)
#pragma unroll
            for (int mi = 0; mi < 2; ++mi)
#pragma unroll
                for (int ni = 0; ni < 4; ++ni)
                    acc[mi][ni] = __builtin_amdgcn_mfma_f32_16x16x32_f16(a[mi][kk], b[ni][kk], acc[mi][ni], 0, 0, 0);
    }
    // epilogue 1: relu+bias, f16-quantize, swizzled store into Ts
#pragma unroll
    for (int ni = 0; ni < 4; ++ni) {
        int col = wn * 64 + ni * 16 + r;
        float bv = b1[col];
#pragma unroll
        for (int mi = 0; mi < 2; ++mi)
#pragma unroll
            for (int rr = 0; rr < 4; ++rr) {
                int lrow = wm * 32 + mi * 16 + rg * 4 + rr;
                float v = fmaxf(acc[mi][ni][rr] + bv, 0.f);
                int chunk = (col >> 3) ^ (lrow & 7);
                *(u16*)((char*)Ts + lrow * 512 + chunk * 16 + (col & 7) * 2) = f2h(v);
            }
#pragma unroll
        for (int mi = 0; mi < 2; ++mi) acc[mi][ni] = (floatx4){0.f, 0.f, 0.f, 0.f};
    }

    // phase 2: m = relu(T @ W2^T + b2)
    for (int k0 = 0; k0 < 256; k0 += 64) {
        __syncthreads();
#pragma unroll
        for (int q = 0; q < 4; ++q) {
            int i = q * 512 + tid;
            int nrow = i >> 3;
            int swz = (i & 7) ^ (nrow & 7);
            load_lds16(B2t + (size_t)nrow * 256 + k0 + swz * 8, Bs + q * 4096 + w * 512);
        }
        __syncthreads();
        short8 a[2][2], b[4][2];
#pragma unroll
        for (int mi = 0; mi < 2; ++mi) {
            int lrow = wm * 32 + mi * 16 + r;
#pragma unroll
            for (int kk = 0; kk < 2; ++kk) {
                int ck = ((k0 >> 3) + kk * 4 + rg) ^ (lrow & 7);
                a[mi][kk] = *(const short8*)((const char*)Ts + lrow * 512 + ck * 16);
            }
        }
#pragma unroll
        for (int ni = 0; ni < 4; ++ni) {
            int row = wn * 64 + ni * 16 + r;
#pragma unroll
            for (int kk = 0; kk < 2; ++kk) {
                int ck = (kk * 4 + rg) ^ (row & 7);
                b[ni][kk] = *(const short8*)(Bs + row * 64 + ck * 8);
            }
        }
#pragma unroll
        for (int kk = 0; kk < 2; ++kk)
#pragma unroll
            for (int mi = 0; mi < 2; ++mi)
#pragma unroll
                for (int ni = 0; ni < 4; ++ni)
                    acc[mi][ni] = __builtin_amdgcn_mfma_f32_16x16x32_f16(a[mi][kk], b[ni][kk], acc[mi][ni], 0, 0, 0);
    }

    // epilogue 2: relu+bias, f16 out (stats on quantized values), fused BN partial sums
#pragma unroll
    for (int ni = 0; ni < 4; ++ni) {
        int col = wn * 64 + ni * 16 + r;
        float bv = b2[col];
        float s = 0.f, s2 = 0.f;
#pragma unroll
        for (int mi = 0; mi < 2; ++mi)
#pragma unroll
            for (int rr = 0; rr < 4; ++rr) {
                int row = bm + wm * 32 + mi * 16 + rg * 4 + rr;
                if (row < M) {
                    float v = fmaxf(acc[mi][ni][rr] + bv, 0.f);
                    u16 qb = f2h(v);
                    float vq = hlo((u32)qb);
                    Cout[(size_t)row * 256 + col] = qb;
                    s += vq;
                    s2 += vq * vq;
                }
            }
        s += __shfl_xor(s, 16);
        s += __shfl_xor(s, 32);
        s2 += __shfl_xor(s2, 16);
        s2 += __shfl_xor(s2, 32);
        if (rg == 0) {
            atomicAdd(&sums_out[col], s);
            atomicAdd(&sums_out[256 + col], s2);
        }
    }
}

// ---------------- standalone BN finalize + fp32 out_nodes + pooling (final layer) ----------------

__global__ void bn_pool(const u16* __restrict__ Mb, const float* __restrict__ sums,
                        const float* __restrict__ g, const float* __restrict__ bb,
                        const int* __restrict__ batch, float* __restrict__ out_nodes,
                        float* __restrict__ pooled, int col_off, int n, float inv_n) {
    int w = threadIdx.x >> 6, lane = threadIdx.x & 63;
    int base = blockIdx.x * 64 + w * 16;
    if (base >= n) return;
    int c4 = lane << 2;
    float4 s1 = *(const float4*)(sums + c4);
    float4 s2 = *(const float4*)(sums + 256 + c4);
    float4 g4 = *(const float4*)(g + c4);
    float4 b4 = *(const float4*)(bb + c4);
    float4 sc, sh;
    {
        float mux = s1.x * inv_n, muy = s1.y * inv_n, muz = s1.z * inv_n, muw = s1.w * inv_n;
        sc.x = g4.x / sqrtf(s2.x * inv_n - mux * mux + BN_EPS);
        sc.y = g4.y / sqrtf(s2.y * inv_n - muy * muy + BN_EPS);
        sc.z = g4.z / sqrtf(s2.z * inv_n - muz * muz + BN_EPS);
        sc.w = g4.w / sqrtf(s2.w * inv_n - muw * muw + BN_EPS);
        sh.x = b4.x - mux * sc.x;
        sh.y = b4.y - muy * sc.y;
        sh.z = b4.z - muz * sc.z;
        sh.w = b4.w - muw * sc.w;
    }
    float4 acc = make_float4(0.f, 0.f, 0.f, 0.f);
    int gcur = -1;
    int end = min(base + 16, n);
    for (int row = base; row < end; ++row) {
        uint2 pk = *(const uint2*)(Mb + (size_t)row * 256 + c4);
        float4 o;
        o.x = fmaf(hlo(pk.x), sc.x, sh.x);
        o.y = fmaf(hhi(pk.x), sc.y, sh.y);
        o.z = fmaf(hlo(pk.y), sc.z, sh.z);
        o.w = fmaf(hhi(pk.y), sc.w, sh.w);
        floatx4 ov = {o.x, o.y, o.z, o.w};
        __builtin_nontemporal_store(ov, (floatx4*)(out_nodes + (size_t)row * 768 + col_off + c4));
        int gg = batch[row];
        if (gg != gcur) {
            if (gcur >= 0) {
                float* pp = pooled + (size_t)gcur * 768 + col_off + c4;
                atomicAdd(pp + 0, acc.x);
                atomicAdd(pp + 1, acc.y);
                atomicAdd(pp + 2, acc.z);
                atomicAdd(pp + 3, acc.w);
            }
            gcur = gg;
            acc = o;
        } else {
            acc.x += o.x; acc.y += o.y; acc.z += o.z; acc.w += o.w;
        }
    }
    if (gcur >= 0) {
        float* pp = pooled + (size_t)gcur * 768 + col_off + c4;
        atomicAdd(pp + 0, acc.x);
        atomicAdd(pp + 1, acc.y);
        atomicAdd(pp + 2, acc.z);
        atomicAdd(pp + 3, acc.w);
    }
}

// ---------------- launch ----------------

extern "C" void kernel_launch(void* const* d_in, const int* in_sizes, int n_in,
                              void* d_out, int out_size, void* d_ws, size_t ws_size,
                              hipStream_t stream) {
    const float* x = (const float*)d_in[0];
    const int* esrc = (const int*)d_in[1];
    const int* edst = esrc + N_EDGES;
    const int* batch = (const int*)d_in[2];

    const float* w1[3] = {(const float*)d_in[3], (const float*)d_in[9], (const float*)d_in[15]};
    const float* b1[3] = {(const float*)d_in[4], (const float*)d_in[10], (const float*)d_in[16]};
    const float* w2[3] = {(const float*)d_in[5], (const float*)d_in[11], (const float*)d_in[17]};
    const float* b2[3] = {(const float*)d_in[6], (const float*)d_in[12], (const float*)d_in[18]};
    const float* bng[3] = {(const float*)d_in[7], (const float*)d_in[13], (const float*)d_in[19]};
    const float* bnb[3] = {(const float*)d_in[8], (const float*)d_in[14], (const float*)d_in[20]};

    float* out_pooled = (float*)d_out;
    float* out_nodes = (float*)d_out + (size_t)N_GRAPHS * 768;

    char* p = (char*)d_ws;
    u16* Abf = (u16*)p; p += (size_t)N_NODES * 256 * 2;  // aggregate out (MLP input)
    u16* Mb0 = (u16*)p; p += (size_t)N_NODES * 256 * 2;  // MLP m out, layers 0 & 2
    u16* Mb1 = (u16*)p; p += (size_t)N_NODES * 256 * 2;  // MLP m out, layer 1
    u16* H = (u16*)p;   p += (size_t)N_NODES * 256 * 2;  // f16(x) for layer 0 only
    u16* Wall = (u16*)p; p += (size_t)360448 * 2;        // all transposed weights
    float* sums = (float*)p; p += 3 * 512 * 4;
    int* deg = (int*)p;      p += (size_t)N_NODES * 4;
    const size_t zero_bytes = 3 * 512 * 4 + (size_t)N_NODES * 4;
    int* row_start = (int*)p; p += (size_t)(N_NODES + 1) * 4;
    int* cursor = (int*)p;    p += (size_t)(N_NODES + 1) * 4;
    int* srcs = (int*)p;      p += (size_t)N_EDGES * 4;
    int* bsum = (int*)p;      p += 256 * 4;
    int* boff = (int*)p;      p += 256 * 4;

    const u16* W1t[3] = {Wall, Wall + 32768, Wall + 98304};
    const u16* W2t[3] = {Wall + 163840, Wall + 229376, Wall + 294912};

    const int NBLK = (N_NODES + 255) / 256;  // 196

    hipMemsetAsync(sums, 0, zero_bytes, stream);
    hipMemsetAsync(out_pooled, 0, (size_t)N_GRAPHS * 768 * sizeof(float), stream);

    // CSR build
    count_deg<<<(N_EDGES + 255) / 256, 256, 0, stream>>>(edst, deg, N_EDGES);
    scan_block<<<NBLK, 256, 0, stream>>>(deg, row_start, bsum, N_NODES);
    scan_partials<<<1, 256, 0, stream>>>(bsum, boff, row_start, cursor, NBLK);
    add_offsets<<<NBLK, 256, 0, stream>>>(row_start, cursor, boff, N_NODES);
    fill_csr<<<(N_EDGES + 255) / 256, 256, 0, stream>>>(esrc, edst, cursor, srcs, N_EDGES);

    {
        const int n4 = N_NODES * F_IN / 4;
        const int tot = n4 + 360448;
        convert_all<<<(tot + 255) / 256, 256, 0, stream>>>(
            (const float4*)x, (uint2*)H, n4,
            w1[0], w1[1], w1[2], w2[0], w2[1], w2[2], Wall);
    }

    const int AGRID = (N_NODES + 3) / 4;       // wave per node
    const int MGRID = (N_NODES + 63) / 64;     // 782 MLP blocks
    const int BGRID = (N_NODES + 127) / 128;   // 391 bn blocks (128 rows each, 512 thr)
    const int PBLK = (N_NODES + 63) / 64;      // 782 (final standalone bn_pool)
    const float inv_n = 1.0f / N_NODES;

    // L0: agg(H) -> MLP (no BN partner yet)
    aggregate_v2<128, 0><<<AGRID, 256, 0, stream>>>(H, row_start, srcs, Abf,
                                                    nullptr, nullptr, nullptr, inv_n, N_NODES);
    mlp_bn<128><<<MGRID, 512, 0, stream>>>(Abf, W1t[0], b1[0], W2t[0], b2[0], Mb0, sums,
                                           N_NODES, 0,
                                           nullptr, nullptr, nullptr, nullptr,
                                           nullptr, nullptr, nullptr, 0, inv_n);
    // L1: agg applies BN-0 affine from Mb0; merged kernel = {bn_pool(L0) | mlp(L1)->Mb1}
    aggregate_v2<256, 1><<<AGRID, 256, 0, stream>>>(Mb0, row_start, srcs, Abf,
                                                    sums, bng[0], bnb[0], inv_n, N_NODES);
    mlp_bn<256><<<BGRID + MGRID, 512, 0, stream>>>(Abf, W1t[1], b1[1], W2t[1], b2[1], Mb1, sums + 512,
                                                   N_NODES, BGRID,
                                                   Mb0, sums, bng[0], bnb[0],
                                                   batch, out_nodes, out_pooled, 0, inv_n);
    // L2: agg applies BN-1 affine from Mb1; merged kernel = {bn_pool(L1) | mlp(L2)->Mb0}
    aggregate_v2<256, 1><<<AGRID, 256, 0, stream>>>(Mb1, row_start, srcs, Abf,
                                                    sums + 512, bng[1], bnb[1], inv_n, N_NODES);
    mlp_bn<256><<<BGRID + MGRID, 512, 0, stream>>>(Abf, W1t[2], b1[2], W2t[2], b2[2], Mb0, sums + 1024,
                                                   N_NODES, BGRID,
                                                   Mb1, sums + 512, bng[1], bnb[1],
                                                   batch, out_nodes, out_pooled, 256, inv_n);
    // final output pass (layer 2)
    bn_pool<<<PBLK, 256, 0, stream>>>(Mb0, sums + 1024, bng[2], bnb[2], batch, out_nodes, out_pooled,
                                      512, N_NODES, inv_n);
}